// Round 9
// baseline (223.678 us; speedup 1.0000x reference)
//
#include <hip/hip_runtime.h>
#include <hip/hip_bf16.h>
#include <math.h>

#define Bsz 2
#define Tseq 2048
#define Cdim 1024
#define Hn 16
#define HDim 64
#define Mrows 4096
#define N3 3072
#define QSCALE 0.1803368801111137f   /* 0.125 * log2(e) baked into Q */

typedef __bf16 bf16_t;
typedef __bf16 bf16x4 __attribute__((ext_vector_type(4)));
typedef __bf16 bf16x8 __attribute__((ext_vector_type(8)));
typedef float floatx4 __attribute__((ext_vector_type(4)));

__device__ __forceinline__ void async16(const void* g, void* l) {
    __builtin_amdgcn_global_load_lds(
        (const __attribute__((address_space(1))) void*)g,
        (__attribute__((address_space(3))) void*)l, 16, 0, 0);
}

// ---------------------------------------------------------------------------
// prep: fused fp32->bf16 convert of x + transpose-convert of w_attn, w_proj.
// ---------------------------------------------------------------------------
__global__ __launch_bounds__(256) void prep_kernel(
    const float* __restrict__ x, const float* __restrict__ w_attn,
    const float* __restrict__ w_proj, bf16_t* __restrict__ xb,
    bf16_t* __restrict__ waT, bf16_t* __restrict__ wpT)
{
    __shared__ float Ts[32][33];
    const int bid = blockIdx.x;
    if (bid < 2048) {
        size_t g = (size_t)bid * 256 + threadIdx.x;
        float4 a = *(const float4*)(x + g * 8);
        float4 b = *(const float4*)(x + g * 8 + 4);
        bf16x8 o;
        o[0] = (bf16_t)a.x; o[1] = (bf16_t)a.y; o[2] = (bf16_t)a.z; o[3] = (bf16_t)a.w;
        o[4] = (bf16_t)b.x; o[5] = (bf16_t)b.y; o[6] = (bf16_t)b.z; o[7] = (bf16_t)b.w;
        *(bf16x8*)(xb + g * 8) = o;
        return;
    }
    const float* in; bf16_t* out; int R, C, bx, by;
    if (bid < 5120) {
        int t = bid - 2048; in = w_attn; out = waT; R = Cdim; C = N3;
        bx = t % 96; by = t / 96;
    } else {
        int t = bid - 5120; in = w_proj; out = wpT; R = Cdim; C = Cdim;
        bx = t & 31; by = t >> 5;
    }
    int c0 = bx << 5, r0 = by << 5;
    int lr = threadIdx.x >> 3, lc = (threadIdx.x & 7) << 2;
    float4 v = *(const float4*)(in + (size_t)(r0 + lr) * C + c0 + lc);
    Ts[lr][lc] = v.x; Ts[lr][lc + 1] = v.y; Ts[lr][lc + 2] = v.z; Ts[lr][lc + 3] = v.w;
    __syncthreads();
    bf16x4 o;
    o[0] = (bf16_t)Ts[lc + 0][lr]; o[1] = (bf16_t)Ts[lc + 1][lr];
    o[2] = (bf16_t)Ts[lc + 2][lr]; o[3] = (bf16_t)Ts[lc + 3][lr];
    *(bf16x4*)(out + (size_t)(c0 + lr) * R + r0 + lc) = o;
}

// ---------------------------------------------------------------------------
// QKV GEMM + fused bias + rotary(q,k) + Q pre-scale. BK=64 (16 iters, half
// the barriers of BK=32; LDS 32 KB). q,k -> bf16 (BH,T,HD); v -> bf16
// (BH,HD,T) key-permuted (sigma) for attn's register-direct PV B-operand.
// ---------------------------------------------------------------------------
__global__ __launch_bounds__(256) void gemm_qkv(
    const bf16_t* __restrict__ xb, const bf16_t* __restrict__ waT,
    const float* __restrict__ bias, const float* __restrict__ cosb,
    const float* __restrict__ sinb,
    bf16_t* __restrict__ qb, bf16_t* __restrict__ kb, bf16_t* __restrict__ vt)
{
    __shared__ bf16_t As[128 * 64];    // 16 KB
    __shared__ bf16_t Bs[128 * 64];    // 16 KB
    const int tid = threadIdx.x;
    const int lane = tid & 63, w = tid >> 6;
    const int lm = lane & 15, quad = lane >> 4;
    const int wy = w >> 1, wx = w & 1;
    const int m0 = blockIdx.y << 7, n0 = blockIdx.x << 7;

    const floatx4 fz = {0.f, 0.f, 0.f, 0.f};
    floatx4 acc[4][4];
    #pragma unroll
    for (int i = 0; i < 4; i++)
        #pragma unroll
        for (int j = 0; j < 4; j++) acc[i][j] = fz;

    const bf16_t* Ag = xb + (size_t)m0 * Cdim;
    const bf16_t* Bg = waT + (size_t)n0 * Cdim;

    for (int k0 = 0; k0 < Cdim; k0 += 64) {
        #pragma unroll
        for (int it = 0; it < 4; ++it) {
            int ci = (it << 8) + tid;
            int row = ci >> 3, cq = (ci & 7) ^ (row & 7);
            async16(Ag + (size_t)row * Cdim + k0 + cq * 8,
                    As + (size_t)((it << 8) + (w << 6)) * 8);
            async16(Bg + (size_t)row * Cdim + k0 + cq * 8,
                    Bs + (size_t)((it << 8) + (w << 6)) * 8);
        }
        __syncthreads();
        #pragma unroll
        for (int ks = 0; ks < 2; ++ks) {
            bf16x8 af[4], bfr[4];
            #pragma unroll
            for (int i = 0; i < 4; i++) {
                int row = (wy << 6) + (i << 4) + lm;
                int ph = ((ks << 2) + quad) ^ (row & 7);
                af[i] = *(const bf16x8*)&As[row * 64 + ph * 8];
            }
            #pragma unroll
            for (int j = 0; j < 4; j++) {
                int row = (wx << 6) + (j << 4) + lm;
                int ph = ((ks << 2) + quad) ^ (row & 7);
                bfr[j] = *(const bf16x8*)&Bs[row * 64 + ph * 8];
            }
            #pragma unroll
            for (int i = 0; i < 4; i++)
                #pragma unroll
                for (int j = 0; j < 4; j++)
                    acc[i][j] = __builtin_amdgcn_mfma_f32_16x16x32_bf16(
                        af[i], bfr[j], acc[i][j], 0, 0, 0);
        }
        __syncthreads();
    }

    // epilogue: C/D layout col=lane&15, row=quad*4+reg
    const int sec = n0 >> 10;                 // block-uniform: 0=q 1=k 2=v
    const int mb = m0 + (wy << 6);
    const int nb = n0 + (wx << 6);
    #pragma unroll
    for (int i = 0; i < 4; i++) {
        int mrow0 = mb + (i << 4) + (quad << 2);
        int b = mrow0 >> 11, t0 = mrow0 & 2047;
        #pragma unroll
        for (int j = 0; j < 4; j++) {
            int n = nb + (j << 4) + lm;
            float bi = bias[n];
            int rel = n & 1023;
            int h = rel >> 6, hd = rel & 63;
            if (sec == 2) {
                int tp = (t0 & ~31) | (((t0 >> 2) & 3) << 3) | (((t0 >> 4) & 1) << 2);
                bf16x4 pk;
                #pragma unroll
                for (int r = 0; r < 4; r++) pk[r] = (bf16_t)(acc[i][j][r] + bi);
                *(bf16x4*)&vt[((size_t)(b * Hn + h) * HDim + hd) * Tseq + tp] = pk;
            } else {
                bf16_t* dst = (sec == 0) ? qb : kb;
                const int ih = hd >> 1;
                const bool ev = !(hd & 1);
                #pragma unroll
                for (int r = 0; r < 4; r++) {
                    int t = t0 + r;
                    float v = acc[i][j][r] + bi;
                    float x = __shfl_xor(v, 1);        // rotary pair partner
                    float c = cosb[t * 32 + ih], s = sinb[t * 32 + ih];
                    float rv = ev ? (v * c - x * s) : (x * s + v * c);
                    if (sec == 0) rv *= QSCALE;
                    dst[((size_t)(b * Hn + h) * Tseq + t) * HDim + hd] = (bf16_t)rv;
                }
            }
        }
    }
}

// ---------------------------------------------------------------------------
// Flash attention. SINGLE-TILE blocks: grid 32(tile) x 32(bh) = 1024 blocks
// -> 4 blocks/CU (r8's pair design was grid-capped at 2 blocks/CU,
// Occupancy 17%). qt = 31 - blockIdx.x so heavy blocks dispatch first.
// 256 threads; wave owns 16 q-rows; kt range 0..qt uniform across waves.
// NO-MAX softmax (scores bounded): P=exp2(s) bf16, l=sum, normalize at end.
// PV = V^T P^T via bf16 x32, key permutation sigma baked into vt.
// 32 KB LDS dbuf K/V. Plain launch_bounds (min-waves clause spills — r5).
// ---------------------------------------------------------------------------
__global__ __launch_bounds__(256) void attn_mfma(
    const bf16_t* __restrict__ qb, const bf16_t* __restrict__ kb,
    const bf16_t* __restrict__ vt, bf16_t* __restrict__ yb)
{
    __shared__ bf16_t Ks[2][64 * 64];       // 16 KB dbuf
    __shared__ bf16_t VTs[2][64 * 64];      // 16 KB dbuf

    const int qt = 31 - blockIdx.x;          // heavy first
    const int bh = blockIdx.y;
    const int b = bh >> 4, h = bh & 15;
    const int tid = threadIdx.x;
    const int w4 = tid >> 6, lane = tid & 63, lm = lane & 15, quad = lane >> 4;
    const int nk = qt + 1;                   // kt = 0 .. qt

    // stage K/V tile 0
    {
        const bf16_t* Kg = kb + (size_t)bh * Tseq * HDim;
        const bf16_t* Vg = vt + (size_t)bh * HDim * Tseq;
        #pragma unroll
        for (int it = 0; it < 2; ++it) {
            int ci = (it << 8) + tid;
            int row = ci >> 3, cq = (ci & 7) ^ (row & 7);
            async16(Kg + row * HDim + cq * 8, &Ks[0][((it << 8) + (w4 << 6)) * 8]);
            async16(Vg + (size_t)row * Tseq + cq * 8, &VTs[0][((it << 8) + (w4 << 6)) * 8]);
        }
    }

    // loop-invariant Q fragments straight from global (B-operand: n=lm, k)
    const int qq = (qt << 6) + (w4 << 4) + lm;
    bf16x8 qf[2];
    {
        const bf16_t* Qg = qb + ((size_t)bh * Tseq + qq) * HDim;
        #pragma unroll
        for (int ks = 0; ks < 2; ++ks)
            qf[ks] = *(const bf16x8*)(Qg + (ks << 5) + (quad << 3));
    }
    __syncthreads();

    const floatx4 fz = {0.f, 0.f, 0.f, 0.f};
    floatx4 o_[4];                           // O^T: [d-subtile]
    #pragma unroll
    for (int f = 0; f < 4; ++f) o_[f] = fz;
    float l_ = 0.f;

    for (int kt = 0; kt < nk; ++kt) {
        const int cb = kt & 1;
        if (kt + 1 < nk) {                    // prefetch next K/V tile
            const int nb2 = cb ^ 1;
            const bf16_t* Kg = kb + ((size_t)bh * Tseq + ((kt + 1) << 6)) * HDim;
            const bf16_t* Vg = vt + (size_t)bh * HDim * Tseq + ((kt + 1) << 6);
            #pragma unroll
            for (int it = 0; it < 2; ++it) {
                int ci = (it << 8) + tid;
                int row = ci >> 3, cq = (ci & 7) ^ (row & 7);
                async16(Kg + row * HDim + cq * 8, &Ks[nb2][((it << 8) + (w4 << 6)) * 8]);
                async16(Vg + (size_t)row * Tseq + cq * 8, &VTs[nb2][((it << 8) + (w4 << 6)) * 8]);
            }
        }

        // S^T = K Q^T
        floatx4 st[4];
        #pragma unroll
        for (int sub = 0; sub < 4; ++sub) st[sub] = fz;
        #pragma unroll
        for (int ks = 0; ks < 2; ++ks) {
            bf16x8 kf[4];
            #pragma unroll
            for (int sub = 0; sub < 4; ++sub) {
                int krow = (sub << 4) + lm;
                int kc = ((ks << 2) + quad) ^ (krow & 7);
                kf[sub] = *(const bf16x8*)&Ks[cb][krow * 64 + kc * 8];
            }
            #pragma unroll
            for (int sub = 0; sub < 4; ++sub)
                st[sub] = __builtin_amdgcn_mfma_f32_16x16x32_bf16(
                    kf[sub], qf[ks], st[sub], 0, 0, 0);
        }

        // no-max softmax: P = exp2(s) (bf16), l += sum(P)
        bf16x8 pf[2];
        {
            const bool dm = (kt == qt);
            float rs = 0.f;
            #pragma unroll
            for (int cc = 0; cc < 2; ++cc)
                #pragma unroll
                for (int jj = 0; jj < 8; ++jj) {
                    int sub = (cc << 1) + (jj >> 2), r = jj & 3;
                    float val = st[sub][r];
                    if (dm) {
                        int key = (kt << 6) + (sub << 4) + (quad << 2) + r;
                        if (key > qq) val = -3e38f;
                    }
                    float p = exp2f(val);
                    rs += p;
                    pf[cc][jj] = (bf16_t)p;
                }
            rs += __shfl_xor(rs, 16);
            rs += __shfl_xor(rs, 32);
            l_ += rs;
        }

        // O^T += V^T P^T (bf16 x32)
        #pragma unroll
        for (int cc = 0; cc < 2; ++cc) {
            bf16x8 vf[4];
            #pragma unroll
            for (int f = 0; f < 4; ++f) {
                int vrow = (f << 4) + lm;
                int vc = ((cc << 2) + quad) ^ (vrow & 7);
                vf[f] = *(const bf16x8*)&VTs[cb][vrow * 64 + vc * 8];
            }
            #pragma unroll
            for (int f = 0; f < 4; ++f)
                o_[f] = __builtin_amdgcn_mfma_f32_16x16x32_bf16(
                    vf[f], pf[cc], o_[f], 0, 0, 0);
        }
        __syncthreads();
    }

    // epilogue: lane holds q=qq, d = f*16+quad*4+r
    {
        float inv = 1.f / l_;
        size_t base = ((size_t)(b * Tseq) + qq) * Cdim + (h << 6) + (quad << 2);
        #pragma unroll
        for (int f = 0; f < 4; ++f) {
            bf16x4 ov;
            #pragma unroll
            for (int r = 0; r < 4; ++r) ov[r] = (bf16_t)(o_[f][r] * inv);
            *(bf16x4*)&yb[base + (f << 4)] = ov;
        }
    }
}

// ---------------------------------------------------------------------------
// Proj GEMM: (4096x1024) @ (1024x1024) + bias -> fp32 out. BK=64 (16 iters;
// at 256 blocks = 1 block/CU barriers can't overlap — halving them is the
// only lever).
// ---------------------------------------------------------------------------
__global__ __launch_bounds__(256) void gemm_proj(
    const bf16_t* __restrict__ yb, const bf16_t* __restrict__ wpT,
    const float* __restrict__ bias, float* __restrict__ out)
{
    __shared__ bf16_t As[128 * 64];
    __shared__ bf16_t Bs[128 * 64];
    const int tid = threadIdx.x;
    const int lane = tid & 63, w = tid >> 6;
    const int lm = lane & 15, quad = lane >> 4;
    const int wy = w >> 1, wx = w & 1;
    const int m0 = blockIdx.y << 7, n0 = blockIdx.x << 7;

    const floatx4 fz = {0.f, 0.f, 0.f, 0.f};
    floatx4 acc[4][4];
    #pragma unroll
    for (int i = 0; i < 4; i++)
        #pragma unroll
        for (int j = 0; j < 4; j++) acc[i][j] = fz;

    const bf16_t* Ag = yb + (size_t)m0 * Cdim;
    const bf16_t* Bg = wpT + (size_t)n0 * Cdim;

    for (int k0 = 0; k0 < Cdim; k0 += 64) {
        #pragma unroll
        for (int it = 0; it < 4; ++it) {
            int ci = (it << 8) + tid;
            int row = ci >> 3, cq = (ci & 7) ^ (row & 7);
            async16(Ag + (size_t)row * Cdim + k0 + cq * 8,
                    As + (size_t)((it << 8) + (w << 6)) * 8);
            async16(Bg + (size_t)row * Cdim + k0 + cq * 8,
                    Bs + (size_t)((it << 8) + (w << 6)) * 8);
        }
        __syncthreads();
        #pragma unroll
        for (int ks = 0; ks < 2; ++ks) {
            bf16x8 af[4], bfr[4];
            #pragma unroll
            for (int i = 0; i < 4; i++) {
                int row = (wy << 6) + (i << 4) + lm;
                int ph = ((ks << 2) + quad) ^ (row & 7);
                af[i] = *(const bf16x8*)&As[row * 64 + ph * 8];
            }
            #pragma unroll
            for (int j = 0; j < 4; j++) {
                int row = (wx << 6) + (j << 4) + lm;
                int ph = ((ks << 2) + quad) ^ (row & 7);
                bfr[j] = *(const bf16x8*)&Bs[row * 64 + ph * 8];
            }
            #pragma unroll
            for (int i = 0; i < 4; i++)
                #pragma unroll
                for (int j = 0; j < 4; j++)
                    acc[i][j] = __builtin_amdgcn_mfma_f32_16x16x32_bf16(
                        af[i], bfr[j], acc[i][j], 0, 0, 0);
        }
        __syncthreads();
    }

    const int mb = m0 + (wy << 6);
    const int nb = n0 + (wx << 6);
    #pragma unroll
    for (int i = 0; i < 4; i++) {
        int mrow0 = mb + (i << 4) + (quad << 2);
        #pragma unroll
        for (int j = 0; j < 4; j++) {
            int n = nb + (j << 4) + lm;
            float bi = bias[n];
            #pragma unroll
            for (int r = 0; r < 4; r++)
                out[(size_t)(mrow0 + r) * Cdim + n] = acc[i][j][r] + bi;
        }
    }
}

extern "C" void kernel_launch(void* const* d_in, const int* in_sizes, int n_in,
                              void* d_out, int out_size, void* d_ws, size_t ws_size,
                              hipStream_t stream) {
    const float* x      = (const float*)d_in[0];
    const float* cosb   = (const float*)d_in[1];
    const float* sinb   = (const float*)d_in[2];
    const float* w_attn = (const float*)d_in[3];
    const float* b_attn = (const float*)d_in[4];
    const float* w_proj = (const float*)d_in[5];
    const float* b_proj = (const float*)d_in[6];

    char* ws = (char*)d_ws;
    bf16_t* xb  = (bf16_t*)(ws);                       //  8 MB: x bf16 (M,K)
    bf16_t* waT = (bf16_t*)(ws + (size_t)(8 << 20));   //  6 MB: w_attn^T (N,K)
    bf16_t* wpT = (bf16_t*)(ws + (size_t)(14 << 20));  //  2 MB: w_proj^T (N,K)
    bf16_t* qb  = (bf16_t*)(ws + (size_t)(16 << 20));  //  8 MB: q bf16 (BH,T,HD), pre-scaled
    bf16_t* kb  = (bf16_t*)(ws + (size_t)(24 << 20));  //  8 MB: k bf16 (BH,T,HD)
    bf16_t* vtb = (bf16_t*)(ws + (size_t)(32 << 20));  //  8 MB: v^T bf16 (BH,HD,T), key-permuted
    bf16_t* yb  = (bf16_t*)(ws + (size_t)(40 << 20));  //  8 MB: attn out (M,C)

    prep_kernel<<<6144, 256, 0, stream>>>(x, w_attn, w_proj, xb, waT, wpT);
    gemm_qkv<<<dim3(24, 32), 256, 0, stream>>>(xb, waT, b_attn, cosb, sinb, qb, kb, vtb);
    attn_mfma<<<dim3(32, 32), 256, 0, stream>>>(qb, kb, vtb, yb);
    gemm_proj<<<dim3(8, 32), 256, 0, stream>>>(yb, wpT, b_proj, (float*)d_out);
}

// Round 10
// 213.633 us; speedup vs baseline: 1.0470x; 1.0470x over previous
//
#include <hip/hip_runtime.h>
#include <hip/hip_bf16.h>
#include <math.h>

#define Bsz 2
#define Tseq 2048
#define Cdim 1024
#define Hn 16
#define HDim 64
#define Mrows 4096
#define N3 3072
#define QSCALE 0.1803368801111137f   /* 0.125 * log2(e) baked into Q */

typedef __bf16 bf16_t;
typedef __bf16 bf16x4 __attribute__((ext_vector_type(4)));
typedef __bf16 bf16x8 __attribute__((ext_vector_type(8)));
typedef float floatx4 __attribute__((ext_vector_type(4)));

__device__ __forceinline__ void async16(const void* g, void* l) {
    __builtin_amdgcn_global_load_lds(
        (const __attribute__((address_space(1))) void*)g,
        (__attribute__((address_space(3))) void*)l, 16, 0, 0);
}

// ---------------------------------------------------------------------------
// prep: fused fp32->bf16 convert of x + transpose-convert of w_attn, w_proj.
// ---------------------------------------------------------------------------
__global__ __launch_bounds__(256) void prep_kernel(
    const float* __restrict__ x, const float* __restrict__ w_attn,
    const float* __restrict__ w_proj, bf16_t* __restrict__ xb,
    bf16_t* __restrict__ waT, bf16_t* __restrict__ wpT)
{
    __shared__ float Ts[32][33];
    const int bid = blockIdx.x;
    if (bid < 2048) {
        size_t g = (size_t)bid * 256 + threadIdx.x;
        float4 a = *(const float4*)(x + g * 8);
        float4 b = *(const float4*)(x + g * 8 + 4);
        bf16x8 o;
        o[0] = (bf16_t)a.x; o[1] = (bf16_t)a.y; o[2] = (bf16_t)a.z; o[3] = (bf16_t)a.w;
        o[4] = (bf16_t)b.x; o[5] = (bf16_t)b.y; o[6] = (bf16_t)b.z; o[7] = (bf16_t)b.w;
        *(bf16x8*)(xb + g * 8) = o;
        return;
    }
    const float* in; bf16_t* out; int R, C, bx, by;
    if (bid < 5120) {
        int t = bid - 2048; in = w_attn; out = waT; R = Cdim; C = N3;
        bx = t % 96; by = t / 96;
    } else {
        int t = bid - 5120; in = w_proj; out = wpT; R = Cdim; C = Cdim;
        bx = t & 31; by = t >> 5;
    }
    int c0 = bx << 5, r0 = by << 5;
    int lr = threadIdx.x >> 3, lc = (threadIdx.x & 7) << 2;
    float4 v = *(const float4*)(in + (size_t)(r0 + lr) * C + c0 + lc);
    Ts[lr][lc] = v.x; Ts[lr][lc + 1] = v.y; Ts[lr][lc + 2] = v.z; Ts[lr][lc + 3] = v.w;
    __syncthreads();
    bf16x4 o;
    o[0] = (bf16_t)Ts[lc + 0][lr]; o[1] = (bf16_t)Ts[lc + 1][lr];
    o[2] = (bf16_t)Ts[lc + 2][lr]; o[3] = (bf16_t)Ts[lc + 3][lr];
    *(bf16x4*)(out + (size_t)(c0 + lr) * R + r0 + lc) = o;
}

// ---------------------------------------------------------------------------
// QKV GEMM (r8-measured BK=32 version) + fused bias + rotary(q,k) + Q scale.
// q,k -> bf16 (BH,T,HD); v -> bf16 (BH,HD,T) key-permuted (sigma).
// ---------------------------------------------------------------------------
__global__ __launch_bounds__(256) void gemm_qkv(
    const bf16_t* __restrict__ xb, const bf16_t* __restrict__ waT,
    const float* __restrict__ bias, const float* __restrict__ cosb,
    const float* __restrict__ sinb,
    bf16_t* __restrict__ qb, bf16_t* __restrict__ kb, bf16_t* __restrict__ vt)
{
    __shared__ bf16_t As[128 * 32];
    __shared__ bf16_t Bs[128 * 32];
    const int tid = threadIdx.x;
    const int lane = tid & 63, w = tid >> 6;
    const int lm = lane & 15, quad = lane >> 4;
    const int wy = w >> 1, wx = w & 1;
    const int m0 = blockIdx.y << 7, n0 = blockIdx.x << 7;

    const floatx4 fz = {0.f, 0.f, 0.f, 0.f};
    floatx4 acc[4][4];
    #pragma unroll
    for (int i = 0; i < 4; i++)
        #pragma unroll
        for (int j = 0; j < 4; j++) acc[i][j] = fz;

    const bf16_t* Ag = xb + (size_t)m0 * Cdim;
    const bf16_t* Bg = waT + (size_t)n0 * Cdim;

    for (int k0 = 0; k0 < Cdim; k0 += 32) {
        #pragma unroll
        for (int it = 0; it < 2; ++it) {
            int ci = (w << 7) + (it << 6) + lane;
            int row = ci >> 2, cq = (ci & 3) ^ (row & 3);
            async16(Ag + (size_t)row * Cdim + k0 + cq * 8, As + ((w << 7) + (it << 6)) * 8);
            async16(Bg + (size_t)row * Cdim + k0 + cq * 8, Bs + ((w << 7) + (it << 6)) * 8);
        }
        __syncthreads();
        bf16x8 af[4], bfr[4];
        #pragma unroll
        for (int i = 0; i < 4; i++) {
            int row = (wy << 6) + (i << 4) + lm;
            int cq = quad ^ (lm & 3);
            af[i] = *(const bf16x8*)&As[row * 32 + cq * 8];
        }
        #pragma unroll
        for (int j = 0; j < 4; j++) {
            int row = (wx << 6) + (j << 4) + lm;
            int cq = quad ^ (lm & 3);
            bfr[j] = *(const bf16x8*)&Bs[row * 32 + cq * 8];
        }
        #pragma unroll
        for (int i = 0; i < 4; i++)
            #pragma unroll
            for (int j = 0; j < 4; j++)
                acc[i][j] = __builtin_amdgcn_mfma_f32_16x16x32_bf16(af[i], bfr[j], acc[i][j], 0, 0, 0);
        __syncthreads();
    }

    const int sec = n0 >> 10;                 // block-uniform: 0=q 1=k 2=v
    const int mb = m0 + (wy << 6);
    const int nb = n0 + (wx << 6);
    #pragma unroll
    for (int i = 0; i < 4; i++) {
        int mrow0 = mb + (i << 4) + (quad << 2);
        int b = mrow0 >> 11, t0 = mrow0 & 2047;
        #pragma unroll
        for (int j = 0; j < 4; j++) {
            int n = nb + (j << 4) + lm;
            float bi = bias[n];
            int rel = n & 1023;
            int h = rel >> 6, hd = rel & 63;
            if (sec == 2) {
                int tp = (t0 & ~31) | (((t0 >> 2) & 3) << 3) | (((t0 >> 4) & 1) << 2);
                bf16x4 pk;
                #pragma unroll
                for (int r = 0; r < 4; r++) pk[r] = (bf16_t)(acc[i][j][r] + bi);
                *(bf16x4*)&vt[((size_t)(b * Hn + h) * HDim + hd) * Tseq + tp] = pk;
            } else {
                bf16_t* dst = (sec == 0) ? qb : kb;
                const int ih = hd >> 1;
                const bool ev = !(hd & 1);
                #pragma unroll
                for (int r = 0; r < 4; r++) {
                    int t = t0 + r;
                    float v = acc[i][j][r] + bi;
                    float x = __shfl_xor(v, 1);        // rotary pair partner
                    float c = cosb[t * 32 + ih], s = sinb[t * 32 + ih];
                    float rv = ev ? (v * c - x * s) : (x * s + v * c);
                    if (sec == 0) rv *= QSCALE;
                    dst[((size_t)(b * Hn + h) * Tseq + t) * HDim + hd] = (bf16_t)rv;
                }
            }
        }
    }
}

// ---------------------------------------------------------------------------
// Flash attention, SPLIT-K over the r8 pair structure. Grid 1024 blocks:
// (bh 32) x (pp 16 x chunk 2). Block handles q-tiles (pp, 31-pp) for
// INTERLEAVED kt = c, c+2, ... (both tiles' work splits evenly -> uniform
// ~16.75 units/block, 4 blocks/CU — fixes r9's triangular tail AND r8's
// 2-block/CU occupancy cap). NO-MAX softmax makes partials combine by plain
// addition: block writes O^T partial (bf16) + l (fp32); reduce_kernel
// normalizes. Plain launch_bounds (min-waves clause spills — r5).
// ---------------------------------------------------------------------------
__global__ __launch_bounds__(256) void attn_mfma(
    const bf16_t* __restrict__ qb, const bf16_t* __restrict__ kb,
    const bf16_t* __restrict__ vt, bf16_t* __restrict__ op0,
    bf16_t* __restrict__ op1, float* __restrict__ lp0, float* __restrict__ lp1)
{
    __shared__ bf16_t Ks[2][64 * 64];       // 16 KB dbuf
    __shared__ bf16_t VTs[2][64 * 64];      // 16 KB dbuf

    const int pp = blockIdx.x >> 1;
    const int ck = blockIdx.x & 1;           // kt chunk: kt = ck, ck+2, ...
    const int bh = blockIdx.y;
    const int tid = threadIdx.x;
    const int w4 = tid >> 6, lane = tid & 63, lm = lane & 15, quad = lane >> 4;
    const int jt0 = pp, jt1 = 31 - pp;
    const int nk = 32 - pp;                  // kt upper bound

    bf16_t* opart = ck ? op1 : op0;
    float* lpart = ck ? lp1 : lp0;

    // stage K/V tile ck
    {
        const bf16_t* Kg = kb + ((size_t)bh * Tseq + (ck << 6)) * HDim;
        const bf16_t* Vg = vt + (size_t)bh * HDim * Tseq + (ck << 6);
        #pragma unroll
        for (int it = 0; it < 2; ++it) {
            int ci = (it << 8) + tid;
            int row = ci >> 3, cq = (ci & 7) ^ (row & 7);
            async16(Kg + row * HDim + cq * 8, &Ks[0][((it << 8) + (w4 << 6)) * 8]);
            async16(Vg + (size_t)row * Tseq + cq * 8, &VTs[0][((it << 8) + (w4 << 6)) * 8]);
        }
    }

    // loop-invariant Q fragments straight from global (B-operand: n=lm, k)
    bf16x8 qf[2][2];
    #pragma unroll
    for (int t = 0; t < 2; ++t) {
        int qrow = ((t ? jt1 : jt0) << 6) + (w4 << 4) + lm;
        const bf16_t* Qg = qb + ((size_t)bh * Tseq + qrow) * HDim;
        #pragma unroll
        for (int ks = 0; ks < 2; ++ks)
            qf[t][ks] = *(const bf16x8*)(Qg + (ks << 5) + (quad << 3));
    }
    __syncthreads();

    const floatx4 fz = {0.f, 0.f, 0.f, 0.f};
    floatx4 o_[2][4];                        // O^T: [tile][d-subtile]
    #pragma unroll
    for (int t = 0; t < 2; ++t)
        #pragma unroll
        for (int f = 0; f < 4; ++f) o_[t][f] = fz;
    float l_[2] = {0.f, 0.f};
    const int lastk[2] = {pp, 31 - pp};
    const int qq[2] = {(jt0 << 6) + (w4 << 4) + lm, (jt1 << 6) + (w4 << 4) + lm};

    for (int kt = ck; kt < nk; kt += 2) {
        const int cb = (kt >> 1) & 1;
        if (kt + 2 < nk) {                    // prefetch next chunk tile
            const int nb2 = cb ^ 1;
            const bf16_t* Kg = kb + ((size_t)bh * Tseq + ((kt + 2) << 6)) * HDim;
            const bf16_t* Vg = vt + (size_t)bh * HDim * Tseq + ((kt + 2) << 6);
            #pragma unroll
            for (int it = 0; it < 2; ++it) {
                int ci = (it << 8) + tid;
                int row = ci >> 3, cq = (ci & 7) ^ (row & 7);
                async16(Kg + row * HDim + cq * 8, &Ks[nb2][((it << 8) + (w4 << 6)) * 8]);
                async16(Vg + (size_t)row * Tseq + cq * 8, &VTs[nb2][((it << 8) + (w4 << 6)) * 8]);
            }
        }

        // S^T = K Q^T for both tiles (K-fragments shared)
        floatx4 st[2][4];
        #pragma unroll
        for (int t = 0; t < 2; ++t)
            #pragma unroll
            for (int sub = 0; sub < 4; ++sub) st[t][sub] = fz;
        #pragma unroll
        for (int ks = 0; ks < 2; ++ks) {
            bf16x8 kf[4];
            #pragma unroll
            for (int sub = 0; sub < 4; ++sub) {
                int krow = (sub << 4) + lm;
                int kc = ((ks << 2) + quad) ^ (krow & 7);
                kf[sub] = *(const bf16x8*)&Ks[cb][krow * 64 + kc * 8];
            }
            if (kt <= lastk[0])
                #pragma unroll
                for (int sub = 0; sub < 4; ++sub)
                    st[0][sub] = __builtin_amdgcn_mfma_f32_16x16x32_bf16(
                        kf[sub], qf[0][ks], st[0][sub], 0, 0, 0);
            #pragma unroll
            for (int sub = 0; sub < 4; ++sub)
                st[1][sub] = __builtin_amdgcn_mfma_f32_16x16x32_bf16(
                    kf[sub], qf[1][ks], st[1][sub], 0, 0, 0);
        }

        // no-max softmax: P = exp2(s) (bf16), l += sum(P)
        bf16x8 pf[2][2];
        #pragma unroll
        for (int t = 0; t < 2; ++t) {
            if (kt > lastk[t]) continue;
            const bool dm = (kt == lastk[t]);
            float rs = 0.f;
            #pragma unroll
            for (int cc = 0; cc < 2; ++cc)
                #pragma unroll
                for (int jj = 0; jj < 8; ++jj) {
                    int sub = (cc << 1) + (jj >> 2), r = jj & 3;
                    float val = st[t][sub][r];
                    if (dm) {
                        int key = (kt << 6) + (sub << 4) + (quad << 2) + r;
                        if (key > qq[t]) val = -3e38f;
                    }
                    float p = exp2f(val);
                    rs += p;
                    pf[t][cc][jj] = (bf16_t)p;
                }
            rs += __shfl_xor(rs, 16);
            rs += __shfl_xor(rs, 32);
            l_[t] += rs;
        }

        // O^T += V^T P^T (bf16 x32; V-fragments shared across tiles)
        #pragma unroll
        for (int cc = 0; cc < 2; ++cc) {
            bf16x8 vf[4];
            #pragma unroll
            for (int f = 0; f < 4; ++f) {
                int vrow = (f << 4) + lm;
                int vc = ((cc << 2) + quad) ^ (vrow & 7);
                vf[f] = *(const bf16x8*)&VTs[cb][vrow * 64 + vc * 8];
            }
            #pragma unroll
            for (int t = 0; t < 2; ++t) {
                if (kt > lastk[t]) continue;
                #pragma unroll
                for (int f = 0; f < 4; ++f)
                    o_[t][f] = __builtin_amdgcn_mfma_f32_16x16x32_bf16(
                        vf[f], pf[t][cc], o_[t][f], 0, 0, 0);
            }
        }
        __syncthreads();
    }

    // epilogue: write PARTIAL O^T (unnormalized, bf16) + l (fp32)
    #pragma unroll
    for (int t = 0; t < 2; ++t) {
        size_t row_id = (size_t)bh * Tseq + qq[t];
        size_t base = row_id * 64 + (quad << 2);
        #pragma unroll
        for (int f = 0; f < 4; ++f) {
            bf16x4 ov;
            #pragma unroll
            for (int r = 0; r < 4; ++r) ov[r] = (bf16_t)o_[t][f][r];
            *(bf16x4*)&opart[base + (f << 4)] = ov;
        }
        if (quad == 0) lpart[row_id] = l_[t];
    }
}

// ---------------------------------------------------------------------------
// reduce: y[b][t][h*64+d] = (O0+O1)/(l0+l1). One thread per q-row (64 dims,
// contiguous 128B in both partials and yb).
// ---------------------------------------------------------------------------
__global__ __launch_bounds__(256) void reduce_kernel(
    const bf16_t* __restrict__ op0, const bf16_t* __restrict__ op1,
    const float* __restrict__ lp0, const float* __restrict__ lp1,
    bf16_t* __restrict__ yb)
{
    int r = blockIdx.x * 256 + threadIdx.x;       // 0..65535
    int bh = r >> 11, q = r & 2047;
    int b = bh >> 4, h = bh & 15;
    float inv = 1.f / (lp0[r] + lp1[r]);
    const bf16_t* a = op0 + (size_t)r * 64;
    const bf16_t* c = op1 + (size_t)r * 64;
    bf16_t* dst = yb + ((size_t)(b * Tseq + q)) * Cdim + (h << 6);
    #pragma unroll
    for (int v = 0; v < 8; ++v) {
        bf16x8 x0 = *(const bf16x8*)(a + v * 8);
        bf16x8 x1 = *(const bf16x8*)(c + v * 8);
        bf16x8 o;
        #pragma unroll
        for (int e = 0; e < 8; ++e)
            o[e] = (bf16_t)(((float)x0[e] + (float)x1[e]) * inv);
        *(bf16x8*)(dst + v * 8) = o;
    }
}

// ---------------------------------------------------------------------------
// Proj GEMM (r8-measured BK=32 version): + bias -> fp32 out.
// ---------------------------------------------------------------------------
__global__ __launch_bounds__(256) void gemm_proj(
    const bf16_t* __restrict__ yb, const bf16_t* __restrict__ wpT,
    const float* __restrict__ bias, float* __restrict__ out)
{
    __shared__ bf16_t As[128 * 32];
    __shared__ bf16_t Bs[128 * 32];
    const int tid = threadIdx.x;
    const int lane = tid & 63, w = tid >> 6;
    const int lm = lane & 15, quad = lane >> 4;
    const int wy = w >> 1, wx = w & 1;
    const int m0 = blockIdx.y << 7, n0 = blockIdx.x << 7;

    const floatx4 fz = {0.f, 0.f, 0.f, 0.f};
    floatx4 acc[4][4];
    #pragma unroll
    for (int i = 0; i < 4; i++)
        #pragma unroll
        for (int j = 0; j < 4; j++) acc[i][j] = fz;

    const bf16_t* Ag = yb + (size_t)m0 * Cdim;
    const bf16_t* Bg = wpT + (size_t)n0 * Cdim;

    for (int k0 = 0; k0 < Cdim; k0 += 32) {
        #pragma unroll
        for (int it = 0; it < 2; ++it) {
            int ci = (w << 7) + (it << 6) + lane;
            int row = ci >> 2, cq = (ci & 3) ^ (row & 3);
            async16(Ag + (size_t)row * Cdim + k0 + cq * 8, As + ((w << 7) + (it << 6)) * 8);
            async16(Bg + (size_t)row * Cdim + k0 + cq * 8, Bs + ((w << 7) + (it << 6)) * 8);
        }
        __syncthreads();
        bf16x8 af[4], bfr[4];
        #pragma unroll
        for (int i = 0; i < 4; i++) {
            int row = (wy << 6) + (i << 4) + lm;
            int cq = quad ^ (lm & 3);
            af[i] = *(const bf16x8*)&As[row * 32 + cq * 8];
        }
        #pragma unroll
        for (int j = 0; j < 4; j++) {
            int row = (wx << 6) + (j << 4) + lm;
            int cq = quad ^ (lm & 3);
            bfr[j] = *(const bf16x8*)&Bs[row * 32 + cq * 8];
        }
        #pragma unroll
        for (int i = 0; i < 4; i++)
            #pragma unroll
            for (int j = 0; j < 4; j++)
                acc[i][j] = __builtin_amdgcn_mfma_f32_16x16x32_bf16(af[i], bfr[j], acc[i][j], 0, 0, 0);
        __syncthreads();
    }

    const int mb = m0 + (wy << 6);
    const int nb = n0 + (wx << 6);
    #pragma unroll
    for (int i = 0; i < 4; i++) {
        int mrow0 = mb + (i << 4) + (quad << 2);
        #pragma unroll
        for (int j = 0; j < 4; j++) {
            int n = nb + (j << 4) + lm;
            float bi = bias[n];
            #pragma unroll
            for (int r = 0; r < 4; r++)
                out[(size_t)(mrow0 + r) * Cdim + n] = acc[i][j][r] + bi;
        }
    }
}

extern "C" void kernel_launch(void* const* d_in, const int* in_sizes, int n_in,
                              void* d_out, int out_size, void* d_ws, size_t ws_size,
                              hipStream_t stream) {
    const float* x      = (const float*)d_in[0];
    const float* cosb   = (const float*)d_in[1];
    const float* sinb   = (const float*)d_in[2];
    const float* w_attn = (const float*)d_in[3];
    const float* b_attn = (const float*)d_in[4];
    const float* w_proj = (const float*)d_in[5];
    const float* b_proj = (const float*)d_in[6];

    char* ws = (char*)d_ws;
    bf16_t* xb  = (bf16_t*)(ws);                       //  8 MB: x bf16; DEAD after qkv
    bf16_t* waT = (bf16_t*)(ws + (size_t)(8 << 20));   //  6 MB: w_attn^T (N,K)
    bf16_t* wpT = (bf16_t*)(ws + (size_t)(14 << 20));  //  2 MB: w_proj^T (N,K)
    bf16_t* qb  = (bf16_t*)(ws + (size_t)(16 << 20));  //  8 MB: q bf16 (BH,T,HD), pre-scaled
    bf16_t* kb  = (bf16_t*)(ws + (size_t)(24 << 20));  //  8 MB: k bf16 (BH,T,HD)
    bf16_t* vtb = (bf16_t*)(ws + (size_t)(32 << 20));  //  8 MB: v^T bf16 (BH,HD,T), key-permuted
    bf16_t* yb  = (bf16_t*)(ws + (size_t)(40 << 20));  //  8 MB: attn out (M,C)
    bf16_t* op0 = (bf16_t*)(ws);                       //  8 MB: O partial chunk0 (aliases dead xb)
    bf16_t* op1 = (bf16_t*)(ws + (size_t)(48 << 20));  //  8 MB: O partial chunk1
    float*  lp0 = (float*)(ws + (size_t)(56 << 20));   // 256 KB: l partial chunk0
    float*  lp1 = (float*)(ws + (size_t)(56 << 20) + 262144); // 256 KB: l chunk1

    prep_kernel<<<6144, 256, 0, stream>>>(x, w_attn, w_proj, xb, waT, wpT);
    gemm_qkv<<<dim3(24, 32), 256, 0, stream>>>(xb, waT, b_attn, cosb, sinb, qb, kb, vtb);
    attn_mfma<<<dim3(32, 32), 256, 0, stream>>>(qb, kb, vtb, op0, op1, lp0, lp1);
    reduce_kernel<<<256, 256, 0, stream>>>(op0, op1, lp0, lp1, yb);
    gemm_proj<<<dim3(8, 32), 256, 0, stream>>>(yb, wpT, b_proj, (float*)d_out);
}